// Round 11
// baseline (437.439 us; speedup 1.0000x reference)
//
#include <hip/hip_runtime.h>
#include <hip/hip_bf16.h>
#include <hip/hip_fp8.h>

typedef __hip_bfloat16 bf16;
using short8  = __attribute__((ext_vector_type(8))) short;
using float4v = __attribute__((ext_vector_type(4))) float;

static constexpr int N_ = 50000;   // nodes
static constexpr int E_ = 20000;   // hyperedges
static constexpr int M_ = 320000;  // incidence pairs
static constexpr int NPAD_ = 50048;  // 391*128 rows for MFMA grid
static constexpr int NB_E = (E_+255)/256;   // 79
static constexpr int NB_N = (N_+255)/256;   // 196
static constexpr int CVTB_ = 6250;          // 12.8M elems / (256 thr * 8 elem)
static constexpr int HISTB_ = 1250;         // 320K / 256
static constexpr int CVTALLB_ = 1364;
static constexpr int NREP_ = 8;             // histogram replication factor

__device__ __forceinline__ float b2f(bf16 v){ return __bfloat162float(v); }
__device__ __forceinline__ float sigm(float x){ return 1.f/(1.f+__expf(-x)); }
__device__ __forceinline__ float u2f(unsigned short u){ return __uint_as_float(((unsigned)u)<<16); }
__device__ __forceinline__ unsigned short f2u(float f){ bf16 t=__float2bfloat16(f); return *(unsigned short*)&t; }
__device__ __forceinline__ unsigned char f2q(float f){ __hip_fp8_e4m3 q(f); return (unsigned char)q.__x; }
__device__ __forceinline__ float q2f(unsigned char u){ __hip_fp8_e4m3 q; q.__x = (__hip_fp8_storage_t)u; return (float)q; }

// ---------------- sniff + zero replicated counters (launch 1) ----------------
__global__ __launch_bounds__(256) void k_sniffzero(const unsigned short* __restrict__ xb, int* flag,
                                                   int* cnt_e, int* cnt_n){
  int b = blockIdx.x, tid = threadIdx.x;
  if (b == 0){
    int sane = 0;
    for (int i = tid; i < 4096; i += 256){
      unsigned short u = xb[2*i];
      int ex = (u >> 7) & 0xFF;
      if ((u & 0x7FFF) == 0 || (ex >= 117 && ex <= 137)) sane++;
    }
    #pragma unroll
    for (int d=1; d<64; d<<=1) sane += __shfl_xor(sane, d, 64);
    __shared__ int wsh[4];
    if ((tid&63)==0) wsh[tid>>6] = sane;
    __syncthreads();
    if (tid==0){
      int tot = wsh[0]+wsh[1]+wsh[2]+wsh[3];
      *flag = (tot > 2048) ? 1 : 0;    // 1 = bf16 storage
    }
  } else {
    int i = (b-1)*256 + tid;
    if (i < NREP_*E_) cnt_e[i] = 0;
    else if (i < NREP_*E_ + NREP_*N_) cnt_n[i - NREP_*E_] = 0;
  }
}

// ---------------- prep: hist(replicated, FIRST) + cvtall + cvt16 in one launch (launch 2) ----------------
__global__ __launch_bounds__(256) void k_prep(
    const void* __restrict__ x, bf16* __restrict__ h16,
    const void* s0, const void* s1, const void* s2, const void* s3, const void* s4,
    const void* s5, const void* s6, const void* s7, const void* s8, const void* s9,
    float* d0, float* d1, float* d2, float* d3, float* d4,
    float* d5, float* d6, float* d7, float* d8, float* d9,
    const int* __restrict__ eidx, const int* __restrict__ nidx,
    int* cnt_e, int* cnt_n,
    const int* __restrict__ flag){
  int b = blockIdx.x, t = threadIdx.x;
  if (b < HISTB_){
    int m = b*256 + t;
    int rep = b & (NREP_-1);
    if (m < M_){
      atomicAdd(&cnt_e[rep*E_ + eidx[m]],1);
      atomicAdd(&cnt_n[rep*N_ + nidx[m]],1);
    }
    return;
  }
  if (b < HISTB_+CVTALLB_){
    int i = (b-HISTB_)*256 + t;
    const void* src; float* dst; int off;
    if      (i < 1536)            { src=s0; dst=d0; off=i; }
    else if (i < 1536+81920)      { src=s1; dst=d1; off=i-1536; }
    else if (i < 83712+256)       { src=s2; dst=d2; off=i-83712; }
    else if (i < 83968+256)       { src=s3; dst=d3; off=i-83968; }
    else if (i < 84224+8)         { src=s4; dst=d4; off=i-84224; }
    else if (i < 84232+131072)    { src=s5; dst=d5; off=i-84232; }
    else if (i < 215304+131072)   { src=s6; dst=d6; off=i-215304; }
    else if (i < 346376+1536)     { src=s7; dst=d7; off=i-346376; }
    else if (i < 347912+512)      { src=s8; dst=d8; off=i-347912; }
    else if (i < 348424+512)      { src=s9; dst=d9; off=i-348424; }
    else return;
    if (*flag) dst[off] = b2f(((const bf16*)src)[off]);
    else       dst[off] = ((const float*)src)[off];
    return;
  }
  size_t i0 = ((size_t)(b-(HISTB_+CVTALLB_))*256 + t) * 8;   // 6250*256*8 == N_*256
  if (*flag){
    short8 v = *(const short8*)((const unsigned short*)x + i0);
    *(short8*)(h16 + i0) = v;
  } else {
    const float* xf = (const float*)x + i0;
    float4 a = *(const float4*)xf;
    float4 c = *(const float4*)(xf + 4);
    short8 v;
    v[0]=(short)f2u(a.x); v[1]=(short)f2u(a.y); v[2]=(short)f2u(a.z); v[3]=(short)f2u(a.w);
    v[4]=(short)f2u(c.x); v[5]=(short)f2u(c.y); v[6]=(short)f2u(c.z); v[7]=(short)f2u(c.w);
    *(short8*)(h16 + i0) = v;
  }
}

// ---------------- scan phase 1 (sums NREP_ replicated histograms) ----------------
__device__ __forceinline__ void scan1_body(const int* cnt, int* off, int* bsum, int n, int blk){
  int tid = threadIdx.x, lane = tid&63, wid = tid>>6;
  int i = blk*256 + tid;
  int v = 0;
  if (i < n){
    #pragma unroll
    for (int c=0;c<NREP_;++c) v += cnt[c*n + i];
  }
  int s = v;
  #pragma unroll
  for (int d=1; d<64; d<<=1){ int t = __shfl_up(s, d, 64); if (lane>=d) s += t; }
  __shared__ int ws[4]; __shared__ int wo[4];
  if (lane==63) ws[wid] = s;
  __syncthreads();
  if (tid==0){ int a=0; for (int k=0;k<4;k++){ int t=ws[k]; wo[k]=a; a+=t; } bsum[blk]=a; }
  __syncthreads();
  if (i<n) off[i] = wo[wid] + s - v;
}

// scan1 + pre + bpack(with inline wqe) in one launch (launch 3)
__global__ __launch_bounds__(256) void k_scan1w(
    const int* __restrict__ cnt_e, int* __restrict__ eoff, int* bsum_e,
    const int* __restrict__ cnt_n, int* __restrict__ noff, int* bsum_n,
    const float* __restrict__ tq_f, const float* __restrict__ w1_f, const float* __restrict__ b1_f,
    float* __restrict__ pre,
    const float* __restrict__ wv_f, const float* __restrict__ wq_f, const float* __restrict__ ec_f,
    bf16* __restrict__ Bp){
  int b = blockIdx.x;
  if (b < NB_E){ scan1_body(cnt_e, eoff, bsum_e, E_, b); return; }
  if (b < NB_E+NB_N){ scan1_body(cnt_n, noff, bsum_n, N_, b-NB_E); return; }
  int b2 = b - (NB_E+NB_N);
  if (b2 < 3){
    int idx = b2*256 + threadIdx.x;
    if (idx >= 768) return;
    int l = idx / 384, r = idx % 384;
    int t = r / 128, r2 = r % 128;
    int h = r2 >> 5, k = r2 & 31;
    const float* tp = tq_f + ((l*4+h)*3 + t)*64;
    const float* wp = w1_f + (size_t)((l*4+h)*32 + k)*320 + 256;
    float s = b1_f[(l*4+h)*32 + k];
    for (int d=0; d<64; ++d) s += tp[d]*wp[d];
    pre[(l*3+t)*128 + r2] = s;
    return;
  }
  int idx = (b2-3)*256 + threadIdx.x;
  if (idx >= 2*448*256) return;
  int l = idx / (448*256), r = idx % (448*256);
  int c = r >> 8, k = r & 255;
  float v = 0.f;
  if (c < 256){
    int dd = c >> 2, h = c & 3;
    v = wv_f[(size_t)l*65536 + (size_t)(h*64+dd)*256 + k];
  }
  else if (c < 384) v = w1_f[(size_t)l*40960 + (size_t)(c-256)*320 + k];
  else if (c < 396){
    int ht = c-384, h = ht/3, tt = ht%3;       // inline wqe dot (was k_wqe)
    const float* ecp = ec_f + ((l*4+h)*3 + tt)*64;
    const float* wqp = wq_f + (size_t)((l*4+h)*64)*256 + k;
    float s = 0.f;
    for (int o2=0; o2<64; ++o2) s += ecp[o2]*wqp[(size_t)o2*256];
    v = s;
  }
  Bp[idx] = __float2bfloat16(v);
}

// ---------------- scan phases 2+3 merged (launch 4) ----------------
__global__ __launch_bounds__(256) void k_scan23(const int* __restrict__ bsum_e, int* __restrict__ eoff, int* cur_e,
                                                const int* __restrict__ bsum_n, int* __restrict__ noff, int* cur_n){
  int b = blockIdx.x, t = threadIdx.x, lane = t&63, wid = t>>6;
  int nb, n, blk;
  const int* bsum; int* off; int* cur;
  if (b < NB_E){ nb=NB_E; n=E_; bsum=bsum_e; off=eoff; cur=cur_e; blk=b; }
  else         { nb=NB_N; n=N_; bsum=bsum_n; off=noff; cur=cur_n; blk=b-NB_E; }
  int v = (t < blk) ? bsum[t] : 0;   // blk <= 195 < 256
  #pragma unroll
  for (int d=1; d<64; d<<=1) v += __shfl_xor(v, d, 64);
  __shared__ int ws[4];
  if (lane==0) ws[wid] = v;
  __syncthreads();
  int p = ws[0]+ws[1]+ws[2]+ws[3];
  int i = blk*256 + t;
  if (i < n){ int e = off[i] + p; off[i] = e; cur[i] = e; }
  if (blk == nb-1 && t == 0) off[n] = p + bsum[nb-1];
}

// ---------------- fill: precompute per-pair endpoint/position arrays ----------------
__global__ __launch_bounds__(256) void k_fill(const int* __restrict__ eidx, const int* __restrict__ nidx,
                                              int* cur_e, int* cur_n,
                                              int* nofp, int* qofp, int* en){
  int m = blockIdx.x*256 + threadIdx.x;
  if (m < M_){
    int e = eidx[m], n = nidx[m];
    int p = atomicAdd(&cur_e[e],1);
    int q = atomicAdd(&cur_n[n],1);
    nofp[p] = n;
    qofp[p] = q;
    en[q]   = e;
  }
}

// ---------------- MFMA GEMM: LDS-staged, XOR-swizzled, counted vmcnt; V stored fp8 ----------------
__global__ __launch_bounds__(256,3) void k_mgemm(const bf16* __restrict__ A16, const bf16* __restrict__ Bp,
    unsigned char* __restrict__ V8, bf16* __restrict__ Hb16, float* __restrict__ S){
  // bijective XCD swizzle (m204), nwg=2737=8*342+1; x fastest within an XCD -> A-panel L2 reuse
  int g = blockIdx.x;
  int xcd = g & 7, i7 = g >> 3;
  int wgid = (xcd==0) ? i7 : (343 + (xcd-1)*342 + i7);
  int x = wgid % 7, y = wgid / 7;

  int t = threadIdx.x;
  int wid = t >> 6, lane = t & 63;
  int q = lane >> 4, li = lane & 15;
  int row0blk = y*128;
  int col0 = x*64;
  int w32 = wid*32;

  __shared__ char lds[49152];   // [A0 16K][B0 8K][A1 16K][B1 8K]

  float4v acc[2][4];
  #pragma unroll
  for (int i=0;i<2;i++)
    #pragma unroll
    for (int j=0;j<4;j++) acc[i][j] = (float4v)(0.f);

  auto stage = [&](int st, int buf){
    const int k0 = st*64;
    char* lA = lds + (buf ? 24576 : 0);
    char* lB = lds + (buf ? 40960 : 16384);
    const bf16* Asrc = A16 + (size_t)row0blk*256 + k0;
    const bf16* Bsrc = Bp  + (size_t)col0*256 + k0;
    #pragma unroll
    for (int ra=0; ra<4; ++ra){
      int gidx = ra*256 + t;
      int r = gidx >> 3, c = gidx & 7;
      const bf16* src = Asrc + (size_t)r*256 + ((c ^ (r&7)) << 3);
      char* dst = lA + (ra*256 + wid*64)*16;   // wave-uniform base; HW adds lane*16
      __builtin_amdgcn_global_load_lds((const __attribute__((address_space(1))) void*)src,
                                       (__attribute__((address_space(3))) void*)dst, 16, 0, 0);
    }
    #pragma unroll
    for (int rb=0; rb<2; ++rb){
      int gidx = rb*256 + t;
      int r = gidx >> 3, c = gidx & 7;
      const bf16* src = Bsrc + (size_t)r*256 + ((c ^ (r&7)) << 3);
      char* dst = lB + (rb*256 + wid*64)*16;
      __builtin_amdgcn_global_load_lds((const __attribute__((address_space(1))) void*)src,
                                       (__attribute__((address_space(3))) void*)dst, 16, 0, 0);
    }
  };

  stage(0, 0);
  #pragma unroll
  for (int st=0; st<4; ++st){
    int bufc = st & 1;
    if (st < 3) stage(st+1, bufc^1);
    __builtin_amdgcn_sched_barrier(0);
    if (st < 3) asm volatile("s_waitcnt vmcnt(6)" ::: "memory");   // current tile done, next 6 in flight
    else        asm volatile("s_waitcnt vmcnt(0)" ::: "memory");
    __builtin_amdgcn_s_barrier();
    __builtin_amdgcn_sched_barrier(0);

    const char* cA = lds + (bufc ? 24576 : 0);
    const char* cB = lds + (bufc ? 40960 : 16384);
    short8 af[2][2], bfr[4][2];
    #pragma unroll
    for (int i=0;i<2;i++)
      #pragma unroll
      for (int k2=0;k2<2;k2++){
        int row = w32 + i*16 + li;
        int gr = (k2*4 + q) ^ (li & 7);
        af[i][k2] = *(const short8*)(cA + row*128 + gr*16);
      }
    #pragma unroll
    for (int j=0;j<4;j++)
      #pragma unroll
      for (int k2=0;k2<2;k2++){
        int row = j*16 + li;
        int gr = (k2*4 + q) ^ (li & 7);
        bfr[j][k2] = *(const short8*)(cB + row*128 + gr*16);
      }
    #pragma unroll
    for (int k2=0;k2<2;k2++)
      #pragma unroll
      for (int j=0;j<4;j++){
        acc[0][j] = __builtin_amdgcn_mfma_f32_16x16x32_bf16(af[0][k2], bfr[j][k2], acc[0][j],0,0,0);
        acc[1][j] = __builtin_amdgcn_mfma_f32_16x16x32_bf16(af[1][k2], bfr[j][k2], acc[1][j],0,0,0);
      }
    __builtin_amdgcn_sched_barrier(0);
    __builtin_amdgcn_s_barrier();
  }

  int row0 = row0blk + w32;
  #pragma unroll
  for (int i=0;i<2;i++){
    #pragma unroll
    for (int r=0;r<4;r++){
      int grow = row0 + i*16 + q*4 + r;
      if (grow >= N_) continue;
      #pragma unroll
      for (int j=0;j<4;j++){
        int gc = col0 + j*16 + li;
        float v = acc[i][j][r];
        if (gc < 256)      V8  [(size_t)grow*256 + gc]       = f2q(v);               // fp8 (permuted layout)
        else if (gc < 384) Hb16[(size_t)grow*128 + gc - 256] = __float2bfloat16(v);
        else if (gc < 396) S   [(size_t)grow*12  + gc - 384] = v;
      }
    }
  }
}

// ---------------- per-node gate (Hb bf16) ----------------
__global__ __launch_bounds__(256) void k_gate(const unsigned short* __restrict__ Hb16, const float* __restrict__ S,
    const float* __restrict__ pre_l, const float* __restrict__ w2_l, const float* __restrict__ b2_l,
    const int* __restrict__ ntype, float* __restrict__ G){
  int node = blockIdx.x*4 + (threadIdx.x>>6);
  int lane = threadIdx.x & 63;
  if (node >= N_) return;
  int typ = ntype[node];
  const float* pr = pre_l + typ*128;
  float v0 = tanhf(u2f(Hb16[(size_t)node*128 + lane])      + pr[lane]);
  float v1 = tanhf(u2f(Hb16[(size_t)node*128 + 64 + lane]) + pr[64+lane]);
  float p0 = v0 * w2_l[lane];
  float p1 = v1 * w2_l[64+lane];
  #pragma unroll
  for (int d=1; d<32; d<<=1){ p0 += __shfl_xor(p0,d,64); p1 += __shfl_xor(p1,d,64); }
  float at0 = sigm(__shfl(p0, 0,64) + b2_l[0]);
  float at1 = sigm(__shfl(p0,32,64) + b2_l[1]);
  float at2 = sigm(__shfl(p1, 0,64) + b2_l[2]);
  float at3 = sigm(__shfl(p1,32,64) + b2_l[3]);
  if (lane < 12){
    int h = lane / 3, t = lane % 3;
    float sv = S[(size_t)node*12 + lane];
    float lr = (sv > 0.f) ? sv : 0.2f*sv;
    float av = (h==0)? at0 : (h==1)? at1 : (h==2)? at2 : at3;
    G[(size_t)node*12 + t*4 + h] = lr * av;
  }
}

// ---------------- per-edge softmax + edge_feat (fp8 V rows, 8-deep pipelined gather) ----------------
__global__ __launch_bounds__(256) void k_edge(const int* __restrict__ eoff,
    const int* __restrict__ nofp, const int* __restrict__ qofp, const int* __restrict__ etype,
    const float* __restrict__ G, const unsigned char* __restrict__ V8,
    float* __restrict__ attn_n, unsigned short* __restrict__ EF16){
  int e = blockIdx.x*4 + (threadIdx.x>>6);
  int lane = threadIdx.x & 63;
  if (e >= E_) return;
  int beg = eoff[e], end = eoff[e+1];
  int deg = end - beg;
  if (deg == 0) return;
  int t = etype[e];
  float a0=0,a1=0,a2=0,a3=0;

  if (deg <= 64){
    int n = 0;
    float4 g; g.x=g.y=g.z=g.w=-1e30f;
    if (lane < deg){
      n = nofp[beg + lane];
      g = *(const float4*)(G + (size_t)n*12 + t*4);
    }
    float mx0=g.x, mx1=g.y, mx2=g.z, mx3=g.w;
    #pragma unroll
    for (int d=1; d<64; d<<=1){
      mx0=fmaxf(mx0,__shfl_xor(mx0,d,64)); mx1=fmaxf(mx1,__shfl_xor(mx1,d,64));
      mx2=fmaxf(mx2,__shfl_xor(mx2,d,64)); mx3=fmaxf(mx3,__shfl_xor(mx3,d,64));
    }
    float ex0=0,ex1=0,ex2=0,ex3=0;
    if (lane < deg){
      ex0=__expf(g.x-mx0); ex1=__expf(g.y-mx1); ex2=__expf(g.z-mx2); ex3=__expf(g.w-mx3);
    }
    float s0=ex0,s1=ex1,s2=ex2,s3=ex3;
    #pragma unroll
    for (int d=1; d<64; d<<=1){
      s0+=__shfl_xor(s0,d,64); s1+=__shfl_xor(s1,d,64);
      s2+=__shfl_xor(s2,d,64); s3+=__shfl_xor(s3,d,64);
    }
    float4 w; w.x=ex0/s0; w.y=ex1/s1; w.z=ex2/s2; w.w=ex3/s3;
    if (lane < deg){
      int q = qofp[beg + lane];
      *(float4*)(attn_n + (size_t)q*4) = w;
    }
    auto ldrow = [&](int j)->uchar4{
      int nn = __shfl(n, j, 64);
      return *(const uchar4*)(V8 + (size_t)nn*256 + (lane<<2));
    };
    uchar4 v0v,v1v,v2v,v3v,v4v,v5v,v6v,v7v;
    if (deg>0) v0v=ldrow(0);
    if (deg>1) v1v=ldrow(1);
    if (deg>2) v2v=ldrow(2);
    if (deg>3) v3v=ldrow(3);
    if (deg>4) v4v=ldrow(4);
    if (deg>5) v5v=ldrow(5);
    if (deg>6) v6v=ldrow(6);
    if (deg>7) v7v=ldrow(7);
    for (int j=0;j<deg;j+=8){
      { float wx=__shfl(w.x,j,64),wy=__shfl(w.y,j,64),wz=__shfl(w.z,j,64),wq=__shfl(w.w,j,64);
        a0+=wx*q2f(v0v.x); a1+=wy*q2f(v0v.y); a2+=wz*q2f(v0v.z); a3+=wq*q2f(v0v.w);
        if (j+8<deg) v0v=ldrow(j+8); }
      if (j+1<deg){
        float wx=__shfl(w.x,j+1,64),wy=__shfl(w.y,j+1,64),wz=__shfl(w.z,j+1,64),wq=__shfl(w.w,j+1,64);
        a0+=wx*q2f(v1v.x); a1+=wy*q2f(v1v.y); a2+=wz*q2f(v1v.z); a3+=wq*q2f(v1v.w);
        if (j+9<deg) v1v=ldrow(j+9); }
      if (j+2<deg){
        float wx=__shfl(w.x,j+2,64),wy=__shfl(w.y,j+2,64),wz=__shfl(w.z,j+2,64),wq=__shfl(w.w,j+2,64);
        a0+=wx*q2f(v2v.x); a1+=wy*q2f(v2v.y); a2+=wz*q2f(v2v.z); a3+=wq*q2f(v2v.w);
        if (j+10<deg) v2v=ldrow(j+10); }
      if (j+3<deg){
        float wx=__shfl(w.x,j+3,64),wy=__shfl(w.y,j+3,64),wz=__shfl(w.z,j+3,64),wq=__shfl(w.w,j+3,64);
        a0+=wx*q2f(v3v.x); a1+=wy*q2f(v3v.y); a2+=wz*q2f(v3v.z); a3+=wq*q2f(v3v.w);
        if (j+11<deg) v3v=ldrow(j+11); }
      if (j+4<deg){
        float wx=__shfl(w.x,j+4,64),wy=__shfl(w.y,j+4,64),wz=__shfl(w.z,j+4,64),wq=__shfl(w.w,j+4,64);
        a0+=wx*q2f(v4v.x); a1+=wy*q2f(v4v.y); a2+=wz*q2f(v4v.z); a3+=wq*q2f(v4v.w);
        if (j+12<deg) v4v=ldrow(j+12); }
      if (j+5<deg){
        float wx=__shfl(w.x,j+5,64),wy=__shfl(w.y,j+5,64),wz=__shfl(w.z,j+5,64),wq=__shfl(w.w,j+5,64);
        a0+=wx*q2f(v5v.x); a1+=wy*q2f(v5v.y); a2+=wz*q2f(v5v.z); a3+=wq*q2f(v5v.w);
        if (j+13<deg) v5v=ldrow(j+13); }
      if (j+6<deg){
        float wx=__shfl(w.x,j+6,64),wy=__shfl(w.y,j+6,64),wz=__shfl(w.z,j+6,64),wq=__shfl(w.w,j+6,64);
        a0+=wx*q2f(v6v.x); a1+=wy*q2f(v6v.y); a2+=wz*q2f(v6v.z); a3+=wq*q2f(v6v.w);
        if (j+14<deg) v6v=ldrow(j+14); }
      if (j+7<deg){
        float wx=__shfl(w.x,j+7,64),wy=__shfl(w.y,j+7,64),wz=__shfl(w.z,j+7,64),wq=__shfl(w.w,j+7,64);
        a0+=wx*q2f(v7v.x); a1+=wy*q2f(v7v.y); a2+=wz*q2f(v7v.z); a3+=wq*q2f(v7v.w);
        if (j+15<deg) v7v=ldrow(j+15); }
    }
  } else {
    float mx0=-1e30f, mx1=-1e30f, mx2=-1e30f, mx3=-1e30f;
    for (int i=beg+lane; i<end; i+=64){
      int n = nofp[i];
      float4 g = *(const float4*)(G + (size_t)n*12 + t*4);
      mx0=fmaxf(mx0,g.x); mx1=fmaxf(mx1,g.y); mx2=fmaxf(mx2,g.z); mx3=fmaxf(mx3,g.w);
    }
    #pragma unroll
    for (int d=1; d<64; d<<=1){
      mx0=fmaxf(mx0,__shfl_xor(mx0,d,64)); mx1=fmaxf(mx1,__shfl_xor(mx1,d,64));
      mx2=fmaxf(mx2,__shfl_xor(mx2,d,64)); mx3=fmaxf(mx3,__shfl_xor(mx3,d,64));
    }
    float sm0=0,sm1=0,sm2=0,sm3=0;
    for (int i=beg+lane; i<end; i+=64){
      int n = nofp[i];
      float4 g = *(const float4*)(G + (size_t)n*12 + t*4);
      sm0+=__expf(g.x-mx0); sm1+=__expf(g.y-mx1); sm2+=__expf(g.z-mx2); sm3+=__expf(g.w-mx3);
    }
    #pragma unroll
    for (int d=1; d<64; d<<=1){
      sm0+=__shfl_xor(sm0,d,64); sm1+=__shfl_xor(sm1,d,64);
      sm2+=__shfl_xor(sm2,d,64); sm3+=__shfl_xor(sm3,d,64);
    }
    float inv0=1.f/sm0, inv1=1.f/sm1, inv2=1.f/sm2, inv3=1.f/sm3;
    for (int i=beg+lane; i<end; i+=64){
      int n = nofp[i];
      float4 g = *(const float4*)(G + (size_t)n*12 + t*4);
      float4 w;
      w.x=__expf(g.x-mx0)*inv0; w.y=__expf(g.y-mx1)*inv1;
      w.z=__expf(g.z-mx2)*inv2; w.w=__expf(g.w-mx3)*inv3;
      *(float4*)(attn_n + (size_t)qofp[i]*4) = w;
    }
    for (int i=beg; i<end; ++i){
      int n = nofp[i];
      float4 g = *(const float4*)(G + (size_t)n*12 + t*4);
      float w0=__expf(g.x-mx0)*inv0, w1=__expf(g.y-mx1)*inv1;
      float w2=__expf(g.z-mx2)*inv2, w3=__expf(g.w-mx3)*inv3;
      uchar4 v = *(const uchar4*)(V8 + (size_t)n*256 + lane*4);
      a0 += w0*q2f(v.x); a1 += w1*q2f(v.y); a2 += w2*q2f(v.z); a3 += w3*q2f(v.w);
    }
  }
  ushort4 ev; ev.x=f2u(a0); ev.y=f2u(a1); ev.z=f2u(a2); ev.w=f2u(a3);
  *(ushort4*)(EF16 + (size_t)e*256 + lane*4) = ev;
}

// ---------------- per-node gather + residual + LayerNorm (contiguous en/attn_n, 8-deep pipelined) ----------------
__global__ __launch_bounds__(256) void k_node(const int* __restrict__ noff, const int* __restrict__ en,
    const float* __restrict__ attn_n, const unsigned short* __restrict__ EF16,
    const float* __restrict__ lng, const float* __restrict__ lnb,
    bf16* __restrict__ h16, void* __restrict__ outv, const int* __restrict__ flag, int last){
  int n = blockIdx.x*4 + (threadIdx.x>>6);
  int lane = threadIdx.x & 63;
  if (n >= N_) return;
  float f0=0,f1=0,f2=0,f3=0;
  int beg = noff[n], end = noff[n+1];
  int deg = end - beg;
  if (deg > 0 && deg <= 64){
    int i = beg + lane;
    int e = 0;
    float4 w; w.x=w.y=w.z=w.w=0.f;
    if (lane < deg){
      e = en[i];
      w = *(const float4*)(attn_n + (size_t)i*4);
    }
    auto ldrow = [&](int j)->ushort4{
      int ee = __shfl(e, j, 64);
      return *(const ushort4*)(EF16 + (size_t)ee*256 + (lane<<2));
    };
    ushort4 v0v,v1v,v2v,v3v,v4v,v5v,v6v,v7v;
    if (deg>0) v0v=ldrow(0);
    if (deg>1) v1v=ldrow(1);
    if (deg>2) v2v=ldrow(2);
    if (deg>3) v3v=ldrow(3);
    if (deg>4) v4v=ldrow(4);
    if (deg>5) v5v=ldrow(5);
    if (deg>6) v6v=ldrow(6);
    if (deg>7) v7v=ldrow(7);
    for (int j=0;j<deg;j+=8){
      { float wx=__shfl(w.x,j,64),wy=__shfl(w.y,j,64),wz=__shfl(w.z,j,64),wq=__shfl(w.w,j,64);
        f0+=wx*u2f(v0v.x); f1+=wy*u2f(v0v.y); f2+=wz*u2f(v0v.z); f3+=wq*u2f(v0v.w);
        if (j+8<deg) v0v=ldrow(j+8); }
      if (j+1<deg){
        float wx=__shfl(w.x,j+1,64),wy=__shfl(w.y,j+1,64),wz=__shfl(w.z,j+1,64),wq=__shfl(w.w,j+1,64);
        f0+=wx*u2f(v1v.x); f1+=wy*u2f(v1v.y); f2+=wz*u2f(v1v.z); f3+=wq*u2f(v1v.w);
        if (j+9<deg) v1v=ldrow(j+9); }
      if (j+2<deg){
        float wx=__shfl(w.x,j+2,64),wy=__shfl(w.y,j+2,64),wz=__shfl(w.z,j+2,64),wq=__shfl(w.w,j+2,64);
        f0+=wx*u2f(v2v.x); f1+=wy*u2f(v2v.y); f2+=wz*u2f(v2v.z); f3+=wq*u2f(v2v.w);
        if (j+10<deg) v2v=ldrow(j+10); }
      if (j+3<deg){
        float wx=__shfl(w.x,j+3,64),wy=__shfl(w.y,j+3,64),wz=__shfl(w.z,j+3,64),wq=__shfl(w.w,j+3,64);
        f0+=wx*u2f(v3v.x); f1+=wy*u2f(v3v.y); f2+=wz*u2f(v3v.z); f3+=wq*u2f(v3v.w);
        if (j+11<deg) v3v=ldrow(j+11); }
      if (j+4<deg){
        float wx=__shfl(w.x,j+4,64),wy=__shfl(w.y,j+4,64),wz=__shfl(w.z,j+4,64),wq=__shfl(w.w,j+4,64);
        f0+=wx*u2f(v4v.x); f1+=wy*u2f(v4v.y); f2+=wz*u2f(v4v.z); f3+=wq*u2f(v4v.w);
        if (j+12<deg) v4v=ldrow(j+12); }
      if (j+5<deg){
        float wx=__shfl(w.x,j+5,64),wy=__shfl(w.y,j+5,64),wz=__shfl(w.z,j+5,64),wq=__shfl(w.w,j+5,64);
        f0+=wx*u2f(v5v.x); f1+=wy*u2f(v5v.y); f2+=wz*u2f(v5v.z); f3+=wq*u2f(v5v.w);
        if (j+13<deg) v5v=ldrow(j+13); }
      if (j+6<deg){
        float wx=__shfl(w.x,j+6,64),wy=__shfl(w.y,j+6,64),wz=__shfl(w.z,j+6,64),wq=__shfl(w.w,j+6,64);
        f0+=wx*u2f(v6v.x); f1+=wy*u2f(v6v.y); f2+=wz*u2f(v6v.z); f3+=wq*u2f(v6v.w);
        if (j+14<deg) v6v=ldrow(j+14); }
      if (j+7<deg){
        float wx=__shfl(w.x,j+7,64),wy=__shfl(w.y,j+7,64),wz=__shfl(w.z,j+7,64),wq=__shfl(w.w,j+7,64);
        f0+=wx*u2f(v7v.x); f1+=wy*u2f(v7v.y); f2+=wz*u2f(v7v.z); f3+=wq*u2f(v7v.w);
        if (j+15<deg) v7v=ldrow(j+15); }
    }
  } else if (deg > 64){
    for (int i=beg; i<end; ++i){
      int e = en[i];
      float4 w = *(const float4*)(attn_n + (size_t)i*4);
      ushort4 v = *(const ushort4*)(EF16 + (size_t)e*256 + lane*4);
      f0 += w.x*u2f(v.x); f1 += w.y*u2f(v.y); f2 += w.z*u2f(v.z); f3 += w.w*u2f(v.w);
    }
  }
  const bf16* hp = h16 + (size_t)n*256;
  float h0 = b2f(hp[lane])+f0, h1 = b2f(hp[64+lane])+f1, h2 = b2f(hp[128+lane])+f2, h3 = b2f(hp[192+lane])+f3;
  float s = h0+h1+h2+h3;
  #pragma unroll
  for (int d=1; d<64; d<<=1) s += __shfl_xor(s,d,64);
  float mean = s * (1.f/256.f);
  float d0=h0-mean, d1=h1-mean, d2=h2-mean, d3=h3-mean;
  float vv = d0*d0+d1*d1+d2*d2+d3*d3;
  #pragma unroll
  for (int d=1; d<64; d<<=1) vv += __shfl_xor(vv,d,64);
  float rstd = rsqrtf(vv*(1.f/256.f) + 1e-5f);
  float o0 = d0*rstd*lng[lane]     + lnb[lane];
  float o1 = d1*rstd*lng[64+lane]  + lnb[64+lane];
  float o2 = d2*rstd*lng[128+lane] + lnb[128+lane];
  float o3 = d3*rstd*lng[192+lane] + lnb[192+lane];
  if (last){
    if (*flag){
      bf16* op = (bf16*)outv + (size_t)n*256;
      op[lane]=__float2bfloat16(o0); op[64+lane]=__float2bfloat16(o1);
      op[128+lane]=__float2bfloat16(o2); op[192+lane]=__float2bfloat16(o3);
    } else {
      float* op = (float*)outv + (size_t)n*256;
      op[lane]=o0; op[64+lane]=o1; op[128+lane]=o2; op[192+lane]=o3;
    }
  } else {
    bf16* o16 = h16 + (size_t)n*256;
    o16[lane]=__float2bfloat16(o0); o16[64+lane]=__float2bfloat16(o1);
    o16[128+lane]=__float2bfloat16(o2); o16[192+lane]=__float2bfloat16(o3);
  }
}

extern "C" void kernel_launch(void* const* d_in, const int* in_sizes, int n_in,
                              void* d_out, int out_size, void* d_ws, size_t ws_size,
                              hipStream_t stream){
  const void* x    = d_in[0];
  const int* ntype = (const int*)d_in[1];
  const int* etype = (const int*)d_in[2];
  const int* nidx  = (const int*)d_in[3];
  const int* eidx  = (const int*)d_in[4];
  (void)in_sizes; (void)n_in; (void)out_size; (void)ws_size;

  char* ws = (char*)d_ws;
  size_t o = 0;
  auto alloc = [&](size_t b)->char*{ char* r = ws + o; o = (o + b + 255) & ~(size_t)255; return r; };
  int*   flag = (int*)  alloc(256);
  char*  R2   =         alloc((size_t)20000000);          // Hb16+S (gemm->gate) / attn_n+EF16 (edge->node)
  float* G    = (float*)alloc((size_t)N_*12*4);
  float* tq_f  = (float*)alloc(1536*4);
  float* w1_f  = (float*)alloc(81920*4);
  float* b1_f  = (float*)alloc(256*4);
  float* w2_f  = (float*)alloc(256*4);
  float* b2_f  = (float*)alloc(8*4);
  float* wq_f  = (float*)alloc(131072*4);
  float* wv_f  = (float*)alloc(131072*4);
  float* ec_f  = (float*)alloc(1536*4);
  float* lng_f = (float*)alloc(512*4);
  float* lnb_f = (float*)alloc(512*4);
  float* pre   = (float*)alloc(768*4);
  int* cnt_e  = (int*)alloc((size_t)NREP_*E_*4);
  int* cnt_n  = (int*)alloc((size_t)NREP_*N_*4);
  int* eoff   = (int*)alloc((size_t)(E_+1)*4);
  int* noff   = (int*)alloc((size_t)(N_+1)*4);
  int* cur_e  = (int*)alloc((size_t)E_*4);
  int* cur_n  = (int*)alloc((size_t)N_*4);
  int* nofp   = (int*)alloc((size_t)M_*4);
  int* qofp   = (int*)alloc((size_t)M_*4);
  int* en     = (int*)alloc((size_t)M_*4);
  int* bsum_e = (int*)alloc(256*4);
  int* bsum_n = (int*)alloc(256*4);
  bf16* h16   = (bf16*)alloc((size_t)NPAD_*256*2);        // 25.6 MB bf16 hidden state (A for MFMA)
  bf16* Bp    = (bf16*)alloc((size_t)2*448*256*2);
  unsigned char* V8 = (unsigned char*)alloc((size_t)N_*256); // 12.8 MB fp8 interleaved [n][d][h]

  bf16*  Hb16 = (bf16*)R2;                                 // 12.8 MB
  float* S    = (float*)(R2 + 16777216);                   // 2.4 MB
  float* attn_n = (float*)R2;                              // 5.12 MB (node-CSR order)
  unsigned short* EF16 = (unsigned short*)(R2 + 5242880);  // 10.24 MB (ends 15.48M < S)

  // launch 1: sniff + zero replicated counters (8*70000 = 560000 ints)
  k_sniffzero<<<1 + (NREP_*(E_+N_)+255)/256, 256, 0, stream>>>((const unsigned short*)x, flag, cnt_e, cnt_n);
  // launch 2: hist(first, replicated) + cvtall + cvt16(vectorized)
  k_prep<<<HISTB_+CVTALLB_+CVTB_, 256, 0, stream>>>(
      x, h16,
      d_in[5], d_in[6], d_in[7], d_in[8], d_in[9],
      d_in[10], d_in[11], d_in[12], d_in[13], d_in[14],
      tq_f, w1_f, b1_f, w2_f, b2_f, wq_f, wv_f, ec_f, lng_f, lnb_f,
      eidx, nidx, cnt_e, cnt_n, flag);
  // launch 3: scan phase 1 (sums 8 replicas) + pre + bpack(with inline wqe)
  k_scan1w<<<NB_E+NB_N+3+896, 256, 0, stream>>>(
      cnt_e, eoff, bsum_e, cnt_n, noff, bsum_n,
      tq_f, w1_f, b1_f, pre, wv_f, wq_f, ec_f, Bp);
  // launch 4: scan phases 2+3
  k_scan23<<<NB_E+NB_N, 256, 0, stream>>>(bsum_e, eoff, cur_e, bsum_n, noff, cur_n);
  // launch 5: fill per-pair endpoint/position arrays
  k_fill<<<M_/256, 256, 0, stream>>>(eidx, nidx, cur_e, cur_n, nofp, qofp, en);

  for (int l=0; l<2; ++l){
    k_mgemm<<<2737, 256, 0, stream>>>(h16, Bp + (size_t)l*448*256, V8, Hb16, S);
    k_gate<<<12500, 256, 0, stream>>>((const unsigned short*)Hb16, S, pre + l*384,
                                      w2_f + l*128, b2_f + l*4, ntype, G);
    k_edge<<<5000, 256, 0, stream>>>(eoff, nofp, qofp, etype, G, V8, attn_n, EF16);
    k_node<<<12500, 256, 0, stream>>>(noff, en, attn_n, EF16, lng_f + l*256, lnb_f + l*256,
                                      h16, d_out, flag, l==1);
  }
}

// Round 12
// 423.999 us; speedup vs baseline: 1.0317x; 1.0317x over previous
//
#include <hip/hip_runtime.h>
#include <hip/hip_bf16.h>

typedef __hip_bfloat16 bf16;
using short8  = __attribute__((ext_vector_type(8))) short;
using float4v = __attribute__((ext_vector_type(4))) float;

static constexpr int N_ = 50000;   // nodes
static constexpr int E_ = 20000;   // hyperedges
static constexpr int M_ = 320000;  // incidence pairs
static constexpr int NPAD_ = 50048;  // 391*128 rows for MFMA grid
static constexpr int NB_E = (E_+255)/256;   // 79
static constexpr int NB_N = (N_+255)/256;   // 196
static constexpr int CVTB_ = 6250;          // 12.8M elems / (256 thr * 8 elem)
static constexpr int HISTB_ = 1250;         // 320K / 256
static constexpr int CVTALLB_ = 1364;
static constexpr int NREP_ = 8;             // histogram replication factor

__device__ __forceinline__ float b2f(bf16 v){ return __bfloat162float(v); }
__device__ __forceinline__ float sigm(float x){ return 1.f/(1.f+__expf(-x)); }
__device__ __forceinline__ float u2f(unsigned short u){ return __uint_as_float(((unsigned)u)<<16); }
__device__ __forceinline__ unsigned short f2u(float f){ bf16 t=__float2bfloat16(f); return *(unsigned short*)&t; }

// ---------------- sniff + zero replicated counters (launch 1) ----------------
__global__ __launch_bounds__(256) void k_sniffzero(const unsigned short* __restrict__ xb, int* flag,
                                                   int* cnt_e, int* cnt_n){
  int b = blockIdx.x, tid = threadIdx.x;
  if (b == 0){
    int sane = 0;
    for (int i = tid; i < 4096; i += 256){
      unsigned short u = xb[2*i];
      int ex = (u >> 7) & 0xFF;
      if ((u & 0x7FFF) == 0 || (ex >= 117 && ex <= 137)) sane++;
    }
    #pragma unroll
    for (int d=1; d<64; d<<=1) sane += __shfl_xor(sane, d, 64);
    __shared__ int wsh[4];
    if ((tid&63)==0) wsh[tid>>6] = sane;
    __syncthreads();
    if (tid==0){
      int tot = wsh[0]+wsh[1]+wsh[2]+wsh[3];
      *flag = (tot > 2048) ? 1 : 0;    // 1 = bf16 storage
    }
  } else {
    int i = (b-1)*256 + tid;
    if (i < NREP_*E_) cnt_e[i] = 0;
    else if (i < NREP_*E_ + NREP_*N_) cnt_n[i - NREP_*E_] = 0;
  }
}

// ---------------- prep: hist(replicated, FIRST) + cvtall + cvt16 in one launch (launch 2) ----------------
__global__ __launch_bounds__(256) void k_prep(
    const void* __restrict__ x, bf16* __restrict__ h16,
    const void* s0, const void* s1, const void* s2, const void* s3, const void* s4,
    const void* s5, const void* s6, const void* s7, const void* s8, const void* s9,
    float* d0, float* d1, float* d2, float* d3, float* d4,
    float* d5, float* d6, float* d7, float* d8, float* d9,
    const int* __restrict__ eidx, const int* __restrict__ nidx,
    int* cnt_e, int* cnt_n,
    const int* __restrict__ flag){
  int b = blockIdx.x, t = threadIdx.x;
  if (b < HISTB_){
    int m = b*256 + t;
    int rep = b & (NREP_-1);
    if (m < M_){
      atomicAdd(&cnt_e[rep*E_ + eidx[m]],1);
      atomicAdd(&cnt_n[rep*N_ + nidx[m]],1);
    }
    return;
  }
  if (b < HISTB_+CVTALLB_){
    int i = (b-HISTB_)*256 + t;
    const void* src; float* dst; int off;
    if      (i < 1536)            { src=s0; dst=d0; off=i; }
    else if (i < 1536+81920)      { src=s1; dst=d1; off=i-1536; }
    else if (i < 83712+256)       { src=s2; dst=d2; off=i-83712; }
    else if (i < 83968+256)       { src=s3; dst=d3; off=i-83968; }
    else if (i < 84224+8)         { src=s4; dst=d4; off=i-84224; }
    else if (i < 84232+131072)    { src=s5; dst=d5; off=i-84232; }
    else if (i < 215304+131072)   { src=s6; dst=d6; off=i-215304; }
    else if (i < 346376+1536)     { src=s7; dst=d7; off=i-346376; }
    else if (i < 347912+512)      { src=s8; dst=d8; off=i-347912; }
    else if (i < 348424+512)      { src=s9; dst=d9; off=i-348424; }
    else return;
    if (*flag) dst[off] = b2f(((const bf16*)src)[off]);
    else       dst[off] = ((const float*)src)[off];
    return;
  }
  size_t i0 = ((size_t)(b-(HISTB_+CVTALLB_))*256 + t) * 8;   // 6250*256*8 == N_*256
  if (*flag){
    short8 v = *(const short8*)((const unsigned short*)x + i0);
    *(short8*)(h16 + i0) = v;
  } else {
    const float* xf = (const float*)x + i0;
    float4 a = *(const float4*)xf;
    float4 c = *(const float4*)(xf + 4);
    short8 v;
    v[0]=(short)f2u(a.x); v[1]=(short)f2u(a.y); v[2]=(short)f2u(a.z); v[3]=(short)f2u(a.w);
    v[4]=(short)f2u(c.x); v[5]=(short)f2u(c.y); v[6]=(short)f2u(c.z); v[7]=(short)f2u(c.w);
    *(short8*)(h16 + i0) = v;
  }
}

// ---------------- scan phase 1 (sums NREP_ replicated histograms) ----------------
__device__ __forceinline__ void scan1_body(const int* cnt, int* off, int* bsum, int n, int blk){
  int tid = threadIdx.x, lane = tid&63, wid = tid>>6;
  int i = blk*256 + tid;
  int v = 0;
  if (i < n){
    #pragma unroll
    for (int c=0;c<NREP_;++c) v += cnt[c*n + i];
  }
  int s = v;
  #pragma unroll
  for (int d=1; d<64; d<<=1){ int t = __shfl_up(s, d, 64); if (lane>=d) s += t; }
  __shared__ int ws[4]; __shared__ int wo[4];
  if (lane==63) ws[wid] = s;
  __syncthreads();
  if (tid==0){ int a=0; for (int k=0;k<4;k++){ int t=ws[k]; wo[k]=a; a+=t; } bsum[blk]=a; }
  __syncthreads();
  if (i<n) off[i] = wo[wid] + s - v;
}

// scan1 + pre + bpack(with inline wqe) in one launch (launch 3)
__global__ __launch_bounds__(256) void k_scan1w(
    const int* __restrict__ cnt_e, int* __restrict__ eoff, int* bsum_e,
    const int* __restrict__ cnt_n, int* __restrict__ noff, int* bsum_n,
    const float* __restrict__ tq_f, const float* __restrict__ w1_f, const float* __restrict__ b1_f,
    float* __restrict__ pre,
    const float* __restrict__ wv_f, const float* __restrict__ wq_f, const float* __restrict__ ec_f,
    bf16* __restrict__ Bp){
  int b = blockIdx.x;
  if (b < NB_E){ scan1_body(cnt_e, eoff, bsum_e, E_, b); return; }
  if (b < NB_E+NB_N){ scan1_body(cnt_n, noff, bsum_n, N_, b-NB_E); return; }
  int b2 = b - (NB_E+NB_N);
  if (b2 < 3){
    int idx = b2*256 + threadIdx.x;
    if (idx >= 768) return;
    int l = idx / 384, r = idx % 384;
    int t = r / 128, r2 = r % 128;
    int h = r2 >> 5, k = r2 & 31;
    const float* tp = tq_f + ((l*4+h)*3 + t)*64;
    const float* wp = w1_f + (size_t)((l*4+h)*32 + k)*320 + 256;
    float s = b1_f[(l*4+h)*32 + k];
    for (int d=0; d<64; ++d) s += tp[d]*wp[d];
    pre[(l*3+t)*128 + r2] = s;
    return;
  }
  int idx = (b2-3)*256 + threadIdx.x;
  if (idx >= 2*448*256) return;
  int l = idx / (448*256), r = idx % (448*256);
  int c = r >> 8, k = r & 255;
  float v = 0.f;
  if (c < 256){
    int dd = c >> 2, h = c & 3;
    v = wv_f[(size_t)l*65536 + (size_t)(h*64+dd)*256 + k];
  }
  else if (c < 384) v = w1_f[(size_t)l*40960 + (size_t)(c-256)*320 + k];
  else if (c < 396){
    int ht = c-384, h = ht/3, tt = ht%3;       // inline wqe dot (was k_wqe)
    const float* ecp = ec_f + ((l*4+h)*3 + tt)*64;
    const float* wqp = wq_f + (size_t)((l*4+h)*64)*256 + k;
    float s = 0.f;
    for (int o2=0; o2<64; ++o2) s += ecp[o2]*wqp[(size_t)o2*256];
    v = s;
  }
  Bp[idx] = __float2bfloat16(v);
}

// ---------------- scan phases 2+3 merged (launch 4) ----------------
__global__ __launch_bounds__(256) void k_scan23(const int* __restrict__ bsum_e, int* __restrict__ eoff, int* cur_e,
                                                const int* __restrict__ bsum_n, int* __restrict__ noff, int* cur_n){
  int b = blockIdx.x, t = threadIdx.x, lane = t&63, wid = t>>6;
  int nb, n, blk;
  const int* bsum; int* off; int* cur;
  if (b < NB_E){ nb=NB_E; n=E_; bsum=bsum_e; off=eoff; cur=cur_e; blk=b; }
  else         { nb=NB_N; n=N_; bsum=bsum_n; off=noff; cur=cur_n; blk=b-NB_E; }
  int v = (t < blk) ? bsum[t] : 0;   // blk <= 195 < 256
  #pragma unroll
  for (int d=1; d<64; d<<=1) v += __shfl_xor(v, d, 64);
  __shared__ int ws[4];
  if (lane==0) ws[wid] = v;
  __syncthreads();
  int p = ws[0]+ws[1]+ws[2]+ws[3];
  int i = blk*256 + t;
  if (i < n){ int e = off[i] + p; off[i] = e; cur[i] = e; }
  if (blk == nb-1 && t == 0) off[n] = p + bsum[nb-1];
}

// ---------------- fill: precompute per-pair endpoint/position arrays ----------------
// nofp[p] = node id of pair, in EDGE-CSR order      (k_edge reads contiguously)
// qofp[p] = node-CSR slot of pair                    (k_edge scatters attn to node order)
// en[q]   = edge id of pair, in NODE-CSR order       (k_node reads contiguously)
__global__ __launch_bounds__(256) void k_fill(const int* __restrict__ eidx, const int* __restrict__ nidx,
                                              int* cur_e, int* cur_n,
                                              int* nofp, int* qofp, int* en){
  int m = blockIdx.x*256 + threadIdx.x;
  if (m < M_){
    int e = eidx[m], n = nidx[m];
    int p = atomicAdd(&cur_e[e],1);
    int q = atomicAdd(&cur_n[n],1);
    nofp[p] = n;
    qofp[p] = q;
    en[q]   = e;
  }
}

// ---------------- MFMA GEMM: LDS-staged, XOR-swizzled, counted vmcnt ----------------
__global__ __launch_bounds__(256,3) void k_mgemm(const bf16* __restrict__ A16, const bf16* __restrict__ Bp,
    bf16* __restrict__ V16, bf16* __restrict__ Hb16, float* __restrict__ S){
  // bijective XCD swizzle (m204), nwg=2737=8*342+1; x fastest within an XCD -> A-panel L2 reuse
  int g = blockIdx.x;
  int xcd = g & 7, i7 = g >> 3;
  int wgid = (xcd==0) ? i7 : (343 + (xcd-1)*342 + i7);
  int x = wgid % 7, y = wgid / 7;

  int t = threadIdx.x;
  int wid = t >> 6, lane = t & 63;
  int q = lane >> 4, li = lane & 15;
  int row0blk = y*128;
  int col0 = x*64;
  int w32 = wid*32;

  __shared__ char lds[49152];   // [A0 16K][B0 8K][A1 16K][B1 8K]

  float4v acc[2][4];
  #pragma unroll
  for (int i=0;i<2;i++)
    #pragma unroll
    for (int j=0;j<4;j++) acc[i][j] = (float4v)(0.f);

  auto stage = [&](int st, int buf){
    const int k0 = st*64;
    char* lA = lds + (buf ? 24576 : 0);
    char* lB = lds + (buf ? 40960 : 16384);
    const bf16* Asrc = A16 + (size_t)row0blk*256 + k0;
    const bf16* Bsrc = Bp  + (size_t)col0*256 + k0;
    #pragma unroll
    for (int ra=0; ra<4; ++ra){
      int gidx = ra*256 + t;
      int r = gidx >> 3, c = gidx & 7;
      const bf16* src = Asrc + (size_t)r*256 + ((c ^ (r&7)) << 3);
      char* dst = lA + (ra*256 + wid*64)*16;   // wave-uniform base; HW adds lane*16
      __builtin_amdgcn_global_load_lds((const __attribute__((address_space(1))) void*)src,
                                       (__attribute__((address_space(3))) void*)dst, 16, 0, 0);
    }
    #pragma unroll
    for (int rb=0; rb<2; ++rb){
      int gidx = rb*256 + t;
      int r = gidx >> 3, c = gidx & 7;
      const bf16* src = Bsrc + (size_t)r*256 + ((c ^ (r&7)) << 3);
      char* dst = lB + (rb*256 + wid*64)*16;
      __builtin_amdgcn_global_load_lds((const __attribute__((address_space(1))) void*)src,
                                       (__attribute__((address_space(3))) void*)dst, 16, 0, 0);
    }
  };

  stage(0, 0);
  #pragma unroll
  for (int st=0; st<4; ++st){
    int bufc = st & 1;
    if (st < 3) stage(st+1, bufc^1);
    __builtin_amdgcn_sched_barrier(0);
    if (st < 3) asm volatile("s_waitcnt vmcnt(6)" ::: "memory");   // current tile done, next 6 in flight
    else        asm volatile("s_waitcnt vmcnt(0)" ::: "memory");
    __builtin_amdgcn_s_barrier();
    __builtin_amdgcn_sched_barrier(0);

    const char* cA = lds + (bufc ? 24576 : 0);
    const char* cB = lds + (bufc ? 40960 : 16384);
    short8 af[2][2], bfr[4][2];
    #pragma unroll
    for (int i=0;i<2;i++)
      #pragma unroll
      for (int k2=0;k2<2;k2++){
        int row = w32 + i*16 + li;
        int gr = (k2*4 + q) ^ (li & 7);
        af[i][k2] = *(const short8*)(cA + row*128 + gr*16);
      }
    #pragma unroll
    for (int j=0;j<4;j++)
      #pragma unroll
      for (int k2=0;k2<2;k2++){
        int row = j*16 + li;
        int gr = (k2*4 + q) ^ (li & 7);
        bfr[j][k2] = *(const short8*)(cB + row*128 + gr*16);
      }
    #pragma unroll
    for (int k2=0;k2<2;k2++)
      #pragma unroll
      for (int j=0;j<4;j++){
        acc[0][j] = __builtin_amdgcn_mfma_f32_16x16x32_bf16(af[0][k2], bfr[j][k2], acc[0][j],0,0,0);
        acc[1][j] = __builtin_amdgcn_mfma_f32_16x16x32_bf16(af[1][k2], bfr[j][k2], acc[1][j],0,0,0);
      }
    __builtin_amdgcn_sched_barrier(0);
    __builtin_amdgcn_s_barrier();
  }

  int row0 = row0blk + w32;
  #pragma unroll
  for (int i=0;i<2;i++){
    #pragma unroll
    for (int r=0;r<4;r++){
      int grow = row0 + i*16 + q*4 + r;
      if (grow >= N_) continue;
      #pragma unroll
      for (int j=0;j<4;j++){
        int gc = col0 + j*16 + li;
        float v = acc[i][j][r];
        if (gc < 256)      V16 [(size_t)grow*256 + gc]       = __float2bfloat16(v);  // contiguous (permuted)
        else if (gc < 384) Hb16[(size_t)grow*128 + gc - 256] = __float2bfloat16(v);
        else if (gc < 396) S   [(size_t)grow*12  + gc - 384] = v;
      }
    }
  }
}

// ---------------- per-node gate (Hb bf16) ----------------
__global__ __launch_bounds__(256) void k_gate(const unsigned short* __restrict__ Hb16, const float* __restrict__ S,
    const float* __restrict__ pre_l, const float* __restrict__ w2_l, const float* __restrict__ b2_l,
    const int* __restrict__ ntype, float* __restrict__ G){
  int node = blockIdx.x*4 + (threadIdx.x>>6);
  int lane = threadIdx.x & 63;
  if (node >= N_) return;
  int typ = ntype[node];
  const float* pr = pre_l + typ*128;
  float v0 = tanhf(u2f(Hb16[(size_t)node*128 + lane])      + pr[lane]);
  float v1 = tanhf(u2f(Hb16[(size_t)node*128 + 64 + lane]) + pr[64+lane]);
  float p0 = v0 * w2_l[lane];
  float p1 = v1 * w2_l[64+lane];
  #pragma unroll
  for (int d=1; d<32; d<<=1){ p0 += __shfl_xor(p0,d,64); p1 += __shfl_xor(p1,d,64); }
  float at0 = sigm(__shfl(p0, 0,64) + b2_l[0]);
  float at1 = sigm(__shfl(p0,32,64) + b2_l[1]);
  float at2 = sigm(__shfl(p1, 0,64) + b2_l[2]);
  float at3 = sigm(__shfl(p1,32,64) + b2_l[3]);
  if (lane < 12){
    int h = lane / 3, t = lane % 3;
    float sv = S[(size_t)node*12 + lane];
    float lr = (sv > 0.f) ? sv : 0.2f*sv;
    float av = (h==0)? at0 : (h==1)? at1 : (h==2)? at2 : at3;
    G[(size_t)node*12 + t*4 + h] = lr * av;
  }
}

// ---------------- per-edge softmax + edge_feat (contiguous nofp/qofp, 8-deep pipelined gather) ----------------
__global__ __launch_bounds__(256) void k_edge(const int* __restrict__ eoff,
    const int* __restrict__ nofp, const int* __restrict__ qofp, const int* __restrict__ etype,
    const float* __restrict__ G, const unsigned short* __restrict__ V16,
    float* __restrict__ attn_n, unsigned short* __restrict__ EF16){
  int e = blockIdx.x*4 + (threadIdx.x>>6);
  int lane = threadIdx.x & 63;
  if (e >= E_) return;
  int beg = eoff[e], end = eoff[e+1];
  int deg = end - beg;
  if (deg == 0) return;
  int t = etype[e];
  float a0=0,a1=0,a2=0,a3=0;

  if (deg <= 64){
    int n = 0;
    float4 g; g.x=g.y=g.z=g.w=-1e30f;
    if (lane < deg){
      n = nofp[beg + lane];
      g = *(const float4*)(G + (size_t)n*12 + t*4);
    }
    float mx0=g.x, mx1=g.y, mx2=g.z, mx3=g.w;
    #pragma unroll
    for (int d=1; d<64; d<<=1){
      mx0=fmaxf(mx0,__shfl_xor(mx0,d,64)); mx1=fmaxf(mx1,__shfl_xor(mx1,d,64));
      mx2=fmaxf(mx2,__shfl_xor(mx2,d,64)); mx3=fmaxf(mx3,__shfl_xor(mx3,d,64));
    }
    float ex0=0,ex1=0,ex2=0,ex3=0;
    if (lane < deg){
      ex0=__expf(g.x-mx0); ex1=__expf(g.y-mx1); ex2=__expf(g.z-mx2); ex3=__expf(g.w-mx3);
    }
    float s0=ex0,s1=ex1,s2=ex2,s3=ex3;
    #pragma unroll
    for (int d=1; d<64; d<<=1){
      s0+=__shfl_xor(s0,d,64); s1+=__shfl_xor(s1,d,64);
      s2+=__shfl_xor(s2,d,64); s3+=__shfl_xor(s3,d,64);
    }
    float4 w; w.x=ex0/s0; w.y=ex1/s1; w.z=ex2/s2; w.w=ex3/s3;
    if (lane < deg){
      int q = qofp[beg + lane];
      *(float4*)(attn_n + (size_t)q*4) = w;
    }
    auto ldrow = [&](int j)->ushort4{
      int nn = __shfl(n, j, 64);
      return *(const ushort4*)(V16 + (size_t)nn*256 + (lane<<2));
    };
    ushort4 v0v,v1v,v2v,v3v,v4v,v5v,v6v,v7v;
    if (deg>0) v0v=ldrow(0);
    if (deg>1) v1v=ldrow(1);
    if (deg>2) v2v=ldrow(2);
    if (deg>3) v3v=ldrow(3);
    if (deg>4) v4v=ldrow(4);
    if (deg>5) v5v=ldrow(5);
    if (deg>6) v6v=ldrow(6);
    if (deg>7) v7v=ldrow(7);
    for (int j=0;j<deg;j+=8){
      { float wx=__shfl(w.x,j,64),wy=__shfl(w.y,j,64),wz=__shfl(w.z,j,64),wq=__shfl(w.w,j,64);
        a0+=wx*u2f(v0v.x); a1+=wy*u2f(v0v.y); a2+=wz*u2f(v0v.z); a3+=wq*u2f(v0v.w);
        if (j+8<deg) v0v=ldrow(j+8); }
      if (j+1<deg){
        float wx=__shfl(w.x,j+1,64),wy=__shfl(w.y,j+1,64),wz=__shfl(w.z,j+1,64),wq=__shfl(w.w,j+1,64);
        a0+=wx*u2f(v1v.x); a1+=wy*u2f(v1v.y); a2+=wz*u2f(v1v.z); a3+=wq*u2f(v1v.w);
        if (j+9<deg) v1v=ldrow(j+9); }
      if (j+2<deg){
        float wx=__shfl(w.x,j+2,64),wy=__shfl(w.y,j+2,64),wz=__shfl(w.z,j+2,64),wq=__shfl(w.w,j+2,64);
        a0+=wx*u2f(v2v.x); a1+=wy*u2f(v2v.y); a2+=wz*u2f(v2v.z); a3+=wq*u2f(v2v.w);
        if (j+10<deg) v2v=ldrow(j+10); }
      if (j+3<deg){
        float wx=__shfl(w.x,j+3,64),wy=__shfl(w.y,j+3,64),wz=__shfl(w.z,j+3,64),wq=__shfl(w.w,j+3,64);
        a0+=wx*u2f(v3v.x); a1+=wy*u2f(v3v.y); a2+=wz*u2f(v3v.z); a3+=wq*u2f(v3v.w);
        if (j+11<deg) v3v=ldrow(j+11); }
      if (j+4<deg){
        float wx=__shfl(w.x,j+4,64),wy=__shfl(w.y,j+4,64),wz=__shfl(w.z,j+4,64),wq=__shfl(w.w,j+4,64);
        a0+=wx*u2f(v4v.x); a1+=wy*u2f(v4v.y); a2+=wz*u2f(v4v.z); a3+=wq*u2f(v4v.w);
        if (j+12<deg) v4v=ldrow(j+12); }
      if (j+5<deg){
        float wx=__shfl(w.x,j+5,64),wy=__shfl(w.y,j+5,64),wz=__shfl(w.z,j+5,64),wq=__shfl(w.w,j+5,64);
        a0+=wx*u2f(v5v.x); a1+=wy*u2f(v5v.y); a2+=wz*u2f(v5v.z); a3+=wq*u2f(v5v.w);
        if (j+13<deg) v5v=ldrow(j+13); }
      if (j+6<deg){
        float wx=__shfl(w.x,j+6,64),wy=__shfl(w.y,j+6,64),wz=__shfl(w.z,j+6,64),wq=__shfl(w.w,j+6,64);
        a0+=wx*u2f(v6v.x); a1+=wy*u2f(v6v.y); a2+=wz*u2f(v6v.z); a3+=wq*u2f(v6v.w);
        if (j+14<deg) v6v=ldrow(j+14); }
      if (j+7<deg){
        float wx=__shfl(w.x,j+7,64),wy=__shfl(w.y,j+7,64),wz=__shfl(w.z,j+7,64),wq=__shfl(w.w,j+7,64);
        a0+=wx*u2f(v7v.x); a1+=wy*u2f(v7v.y); a2+=wz*u2f(v7v.z); a3+=wq*u2f(v7v.w);
        if (j+15<deg) v7v=ldrow(j+15); }
    }
  } else {
    float mx0=-1e30f, mx1=-1e30f, mx2=-1e30f, mx3=-1e30f;
    for (int i=beg+lane; i<end; i+=64){
      int n = nofp[i];
      float4 g = *(const float4*)(G + (size_t)n*12 + t*4);
      mx0=fmaxf(mx0,g.x); mx1=fmaxf(mx1,g.y); mx2=fmaxf(mx2,g.z); mx3=fmaxf(mx3,g.w);
    }
    #pragma unroll
    for (int d=1; d<64; d<<=1){
      mx0=fmaxf(mx0,__shfl_xor(mx0,d,64)); mx1=fmaxf(mx1,__shfl_xor(mx1,d,64));
      mx2=fmaxf(mx2,__shfl_xor(mx2,d,64)); mx3=fmaxf(mx3,__shfl_xor(mx3,d,64));
    }
    float sm0=0,sm1=0,sm2=0,sm3=0;
    for (int i=beg+lane; i<end; i+=64){
      int n = nofp[i];
      float4 g = *(const float4*)(G + (size_t)n*12 + t*4);
      sm0+=__expf(g.x-mx0); sm1+=__expf(g.y-mx1); sm2+=__expf(g.z-mx2); sm3+=__expf(g.w-mx3);
    }
    #pragma unroll
    for (int d=1; d<64; d<<=1){
      sm0+=__shfl_xor(sm0,d,64); sm1+=__shfl_xor(sm1,d,64);
      sm2+=__shfl_xor(sm2,d,64); sm3+=__shfl_xor(sm3,d,64);
    }
    float inv0=1.f/sm0, inv1=1.f/sm1, inv2=1.f/sm2, inv3=1.f/sm3;
    for (int i=beg+lane; i<end; i+=64){
      int n = nofp[i];
      float4 g = *(const float4*)(G + (size_t)n*12 + t*4);
      float4 w;
      w.x=__expf(g.x-mx0)*inv0; w.y=__expf(g.y-mx1)*inv1;
      w.z=__expf(g.z-mx2)*inv2; w.w=__expf(g.w-mx3)*inv3;
      *(float4*)(attn_n + (size_t)qofp[i]*4) = w;
    }
    for (int i=beg; i<end; ++i){
      int n = nofp[i];
      float4 g = *(const float4*)(G + (size_t)n*12 + t*4);
      float w0=__expf(g.x-mx0)*inv0, w1=__expf(g.y-mx1)*inv1;
      float w2=__expf(g.z-mx2)*inv2, w3=__expf(g.w-mx3)*inv3;
      ushort4 v = *(const ushort4*)(V16 + (size_t)n*256 + lane*4);
      a0 += w0*u2f(v.x); a1 += w1*u2f(v.y); a2 += w2*u2f(v.z); a3 += w3*u2f(v.w);
    }
  }
  ushort4 ev; ev.x=f2u(a0); ev.y=f2u(a1); ev.z=f2u(a2); ev.w=f2u(a3);
  *(ushort4*)(EF16 + (size_t)e*256 + lane*4) = ev;
}

// ---------------- per-node gather + residual + LayerNorm (contiguous en/attn_n, 8-deep pipelined) ----------------
__global__ __launch_bounds__(256) void k_node(const int* __restrict__ noff, const int* __restrict__ en,
    const float* __restrict__ attn_n, const unsigned short* __restrict__ EF16,
    const float* __restrict__ lng, const float* __restrict__ lnb,
    bf16* __restrict__ h16, void* __restrict__ outv, const int* __restrict__ flag, int last){
  int n = blockIdx.x*4 + (threadIdx.x>>6);
  int lane = threadIdx.x & 63;
  if (n >= N_) return;
  float f0=0,f1=0,f2=0,f3=0;
  int beg = noff[n], end = noff[n+1];
  int deg = end - beg;
  if (deg > 0 && deg <= 64){
    int i = beg + lane;
    int e = 0;
    float4 w; w.x=w.y=w.z=w.w=0.f;
    if (lane < deg){
      e = en[i];
      w = *(const float4*)(attn_n + (size_t)i*4);
    }
    auto ldrow = [&](int j)->ushort4{
      int ee = __shfl(e, j, 64);
      return *(const ushort4*)(EF16 + (size_t)ee*256 + (lane<<2));
    };
    ushort4 v0v,v1v,v2v,v3v,v4v,v5v,v6v,v7v;
    if (deg>0) v0v=ldrow(0);
    if (deg>1) v1v=ldrow(1);
    if (deg>2) v2v=ldrow(2);
    if (deg>3) v3v=ldrow(3);
    if (deg>4) v4v=ldrow(4);
    if (deg>5) v5v=ldrow(5);
    if (deg>6) v6v=ldrow(6);
    if (deg>7) v7v=ldrow(7);
    for (int j=0;j<deg;j+=8){
      { float wx=__shfl(w.x,j,64),wy=__shfl(w.y,j,64),wz=__shfl(w.z,j,64),wq=__shfl(w.w,j,64);
        f0+=wx*u2f(v0v.x); f1+=wy*u2f(v0v.y); f2+=wz*u2f(v0v.z); f3+=wq*u2f(v0v.w);
        if (j+8<deg) v0v=ldrow(j+8); }
      if (j+1<deg){
        float wx=__shfl(w.x,j+1,64),wy=__shfl(w.y,j+1,64),wz=__shfl(w.z,j+1,64),wq=__shfl(w.w,j+1,64);
        f0+=wx*u2f(v1v.x); f1+=wy*u2f(v1v.y); f2+=wz*u2f(v1v.z); f3+=wq*u2f(v1v.w);
        if (j+9<deg) v1v=ldrow(j+9); }
      if (j+2<deg){
        float wx=__shfl(w.x,j+2,64),wy=__shfl(w.y,j+2,64),wz=__shfl(w.z,j+2,64),wq=__shfl(w.w,j+2,64);
        f0+=wx*u2f(v2v.x); f1+=wy*u2f(v2v.y); f2+=wz*u2f(v2v.z); f3+=wq*u2f(v2v.w);
        if (j+10<deg) v2v=ldrow(j+10); }
      if (j+3<deg){
        float wx=__shfl(w.x,j+3,64),wy=__shfl(w.y,j+3,64),wz=__shfl(w.z,j+3,64),wq=__shfl(w.w,j+3,64);
        f0+=wx*u2f(v3v.x); f1+=wy*u2f(v3v.y); f2+=wz*u2f(v3v.z); f3+=wq*u2f(v3v.w);
        if (j+11<deg) v3v=ldrow(j+11); }
      if (j+4<deg){
        float wx=__shfl(w.x,j+4,64),wy=__shfl(w.y,j+4,64),wz=__shfl(w.z,j+4,64),wq=__shfl(w.w,j+4,64);
        f0+=wx*u2f(v4v.x); f1+=wy*u2f(v4v.y); f2+=wz*u2f(v4v.z); f3+=wq*u2f(v4v.w);
        if (j+12<deg) v4v=ldrow(j+12); }
      if (j+5<deg){
        float wx=__shfl(w.x,j+5,64),wy=__shfl(w.y,j+5,64),wz=__shfl(w.z,j+5,64),wq=__shfl(w.w,j+5,64);
        f0+=wx*u2f(v5v.x); f1+=wy*u2f(v5v.y); f2+=wz*u2f(v5v.z); f3+=wq*u2f(v5v.w);
        if (j+13<deg) v5v=ldrow(j+13); }
      if (j+6<deg){
        float wx=__shfl(w.x,j+6,64),wy=__shfl(w.y,j+6,64),wz=__shfl(w.z,j+6,64),wq=__shfl(w.w,j+6,64);
        f0+=wx*u2f(v6v.x); f1+=wy*u2f(v6v.y); f2+=wz*u2f(v6v.z); f3+=wq*u2f(v6v.w);
        if (j+14<deg) v6v=ldrow(j+14); }
      if (j+7<deg){
        float wx=__shfl(w.x,j+7,64),wy=__shfl(w.y,j+7,64),wz=__shfl(w.z,j+7,64),wq=__shfl(w.w,j+7,64);
        f0+=wx*u2f(v7v.x); f1+=wy*u2f(v7v.y); f2+=wz*u2f(v7v.z); f3+=wq*u2f(v7v.w);
        if (j+15<deg) v7v=ldrow(j+15); }
    }
  } else if (deg > 64){
    for (int i=beg; i<end; ++i){
      int e = en[i];
      float4 w = *(const float4*)(attn_n + (size_t)i*4);
      ushort4 v = *(const ushort4*)(EF16 + (size_t)e*256 + lane*4);
      f0 += w.x*u2f(v.x); f1 += w.y*u2f(v.y); f2 += w.z*u2f(v.z); f3 += w.w*u2f(v.w);
    }
  }
  const bf16* hp = h16 + (size_t)n*256;
  float h0 = b2f(hp[lane])+f0, h1 = b2f(hp[64+lane])+f1, h2 = b2f(hp[128+lane])+f2, h3 = b2f(hp[192+lane])+f3;
  float s = h0+h1+h2+h3;
  #pragma unroll
  for (int d=1; d<64; d<<=1) s += __shfl_xor(s,d,64);
  float mean = s * (1.f/256.f);
  float d0=h0-mean, d1=h1-mean, d2=h2-mean, d3=h3-mean;
  float vv = d0*d0+d1*d1+d2*d2+d3*d3;
  #pragma unroll
  for (int d=1; d<64; d<<=1) vv += __shfl_xor(vv,d,64);
  float rstd = rsqrtf(vv*(1.f/256.f) + 1e-5f);
  float o0 = d0*rstd*lng[lane]     + lnb[lane];
  float o1 = d1*rstd*lng[64+lane]  + lnb[64+lane];
  float o2 = d2*rstd*lng[128+lane] + lnb[128+lane];
  float o3 = d3*rstd*lng[192+lane] + lnb[192+lane];
  if (last){
    if (*flag){
      bf16* op = (bf16*)outv + (size_t)n*256;
      op[lane]=__float2bfloat16(o0); op[64+lane]=__float2bfloat16(o1);
      op[128+lane]=__float2bfloat16(o2); op[192+lane]=__float2bfloat16(o3);
    } else {
      float* op = (float*)outv + (size_t)n*256;
      op[lane]=o0; op[64+lane]=o1; op[128+lane]=o2; op[192+lane]=o3;
    }
  } else {
    bf16* o16 = h16 + (size_t)n*256;
    o16[lane]=__float2bfloat16(o0); o16[64+lane]=__float2bfloat16(o1);
    o16[128+lane]=__float2bfloat16(o2); o16[192+lane]=__float2bfloat16(o3);
  }
}

extern "C" void kernel_launch(void* const* d_in, const int* in_sizes, int n_in,
                              void* d_out, int out_size, void* d_ws, size_t ws_size,
                              hipStream_t stream){
  const void* x    = d_in[0];
  const int* ntype = (const int*)d_in[1];
  const int* etype = (const int*)d_in[2];
  const int* nidx  = (const int*)d_in[3];
  const int* eidx  = (const int*)d_in[4];
  (void)in_sizes; (void)n_in; (void)out_size; (void)ws_size;

  char* ws = (char*)d_ws;
  size_t o = 0;
  auto alloc = [&](size_t b)->char*{ char* r = ws + o; o = (o + b + 255) & ~(size_t)255; return r; };
  int*   flag = (int*)  alloc(256);
  char*  R2   =         alloc((size_t)20000000);          // Hb16+S (gemm->gate) / attn_n+EF16 (edge->node)
  float* G    = (float*)alloc((size_t)N_*12*4);
  float* tq_f  = (float*)alloc(1536*4);
  float* w1_f  = (float*)alloc(81920*4);
  float* b1_f  = (float*)alloc(256*4);
  float* w2_f  = (float*)alloc(256*4);
  float* b2_f  = (float*)alloc(8*4);
  float* wq_f  = (float*)alloc(131072*4);
  float* wv_f  = (float*)alloc(131072*4);
  float* ec_f  = (float*)alloc(1536*4);
  float* lng_f = (float*)alloc(512*4);
  float* lnb_f = (float*)alloc(512*4);
  float* pre   = (float*)alloc(768*4);
  int* cnt_e  = (int*)alloc((size_t)NREP_*E_*4);
  int* cnt_n  = (int*)alloc((size_t)NREP_*N_*4);
  int* eoff   = (int*)alloc((size_t)(E_+1)*4);
  int* noff   = (int*)alloc((size_t)(N_+1)*4);
  int* cur_e  = (int*)alloc((size_t)E_*4);
  int* cur_n  = (int*)alloc((size_t)N_*4);
  int* nofp   = (int*)alloc((size_t)M_*4);
  int* qofp   = (int*)alloc((size_t)M_*4);
  int* en     = (int*)alloc((size_t)M_*4);
  int* bsum_e = (int*)alloc(256*4);
  int* bsum_n = (int*)alloc(256*4);
  bf16* h16   = (bf16*)alloc((size_t)NPAD_*256*2);        // 25.6 MB bf16 hidden state (A for MFMA)
  bf16* Bp    = (bf16*)alloc((size_t)2*448*256*2);
  bf16* V16   = (bf16*)alloc((size_t)N_*256*2);           // 25.6 MB interleaved [n][d][h]

  bf16*  Hb16 = (bf16*)R2;                                 // 12.8 MB
  float* S    = (float*)(R2 + 16777216);                   // 2.4 MB
  float* attn_n = (float*)R2;                              // 5.12 MB (node-CSR order)
  unsigned short* EF16 = (unsigned short*)(R2 + 5242880);  // 10.24 MB (ends 15.48M < S)

  // launch 1: sniff + zero replicated counters (8*70000 = 560000 ints)
  k_sniffzero<<<1 + (NREP_*(E_+N_)+255)/256, 256, 0, stream>>>((const unsigned short*)x, flag, cnt_e, cnt_n);
  // launch 2: hist(first, replicated) + cvtall + cvt16(vectorized)
  k_prep<<<HISTB_+CVTALLB_+CVTB_, 256, 0, stream>>>(
      x, h16,
      d_in[5], d_in[6], d_in[7], d_in[8], d_in[9],
      d_in[10], d_in[11], d_in[12], d_in[13], d_in[14],
      tq_f, w1_f, b1_f, w2_f, b2_f, wq_f, wv_f, ec_f, lng_f, lnb_f,
      eidx, nidx, cnt_e, cnt_n, flag);
  // launch 3: scan phase 1 (sums 8 replicas) + pre + bpack(with inline wqe)
  k_scan1w<<<NB_E+NB_N+3+896, 256, 0, stream>>>(
      cnt_e, eoff, bsum_e, cnt_n, noff, bsum_n,
      tq_f, w1_f, b1_f, pre, wv_f, wq_f, ec_f, Bp);
  // launch 4: scan phases 2+3
  k_scan23<<<NB_E+NB_N, 256, 0, stream>>>(bsum_e, eoff, cur_e, bsum_n, noff, cur_n);
  // launch 5: fill per-pair endpoint/position arrays
  k_fill<<<M_/256, 256, 0, stream>>>(eidx, nidx, cur_e, cur_n, nofp, qofp, en);

  for (int l=0; l<2; ++l){
    k_mgemm<<<2737, 256, 0, stream>>>(h16, Bp + (size_t)l*448*256, V16, Hb16, S);
    k_gate<<<12500, 256, 0, stream>>>((const unsigned short*)Hb16, S, pre + l*384,
                                      w2_f + l*128, b2_f + l*4, ntype, G);
    k_edge<<<5000, 256, 0, stream>>>(eoff, nofp, qofp, etype, G, (const unsigned short*)V16, attn_n, EF16);
    k_node<<<12500, 256, 0, stream>>>(noff, en, attn_n, EF16, lng_f + l*256, lnb_f + l*256,
                                      h16, d_out, flag, l==1);
  }
}